// Round 2
// baseline (2842.154 us; speedup 1.0000x reference)
//
#include <hip/hip_runtime.h>
#include <hip/hip_bf16.h>
#include <math.h>

typedef float f4 __attribute__((ext_vector_type(4)));

#define NTAGS 600
#define CEw   48
#define HH    256
#define BBATCH 64
#define TSEQ  96
#define CLW   16
#define LMAXD 24
#define NROWS (BBATCH*TSEQ)   /* 6144 */
#define DIN   192             /* WE(128)+CC(64) */
#define KCONV 160             /* 144 padded to /32 */
#define VCD   200

__device__ __forceinline__ float sigf(float x){ return 1.0f/(1.0f+expf(-x)); }

// ---------------- generic tiled f32 GEMM: C[M,N] = A[M,K] * B[N,K]^T + bias ----------------
// MODE 0: A row-major [M,K].  MODE 1: conv sliding window over ce[M rows of 48], K=144 (padded 160).
// ACT: 0 none, 1 tanh.
template<int MODE, int ACT>
__global__ __launch_bounds__(256)
void gemm_k(const float* __restrict__ A, const float* __restrict__ B,
            const float* __restrict__ bias, float* __restrict__ C,
            int M, int N, int K)
{
    __shared__ float As[32][68];
    __shared__ float Bs[32][68];
    const int tid = threadIdx.x;
    const int m0 = blockIdx.x * 64;
    const int n0 = blockIdx.y * 64;
    const int mg = tid >> 4, ng = tid & 15;
    float acc[4][4] = {};
    for (int k0 = 0; k0 < K; k0 += 32) {
        #pragma unroll
        for (int i = 0; i < 8; ++i) {
            int e  = tid + i * 256;
            int kk = e & 31, mm = e >> 5;
            int m = m0 + mm;
            int k = k0 + kk;
            float av;
            if (MODE == 0) {
                av = A[(size_t)m * K + k];
            } else {
                av = 0.0f;
                int p = m & 15;
                if (k < 144 && !(p == 0 && k < 48) && !(p == 15 && k >= 96))
                    av = A[m * 48 + k - 48];      // ce[n*16 + p + k/48 - 1][k%48]
            }
            As[kk][mm] = av;
            int n = n0 + mm;
            Bs[kk][mm] = (n < N) ? B[(size_t)n * K + k] : 0.0f;
        }
        __syncthreads();
        #pragma unroll
        for (int kk = 0; kk < 32; ++kk) {
            f4 a = *reinterpret_cast<const f4*>(&As[kk][mg * 4]);
            f4 b = *reinterpret_cast<const f4*>(&Bs[kk][ng * 4]);
            #pragma unroll
            for (int i = 0; i < 4; ++i)
                #pragma unroll
                for (int j = 0; j < 4; ++j)
                    acc[i][j] = fmaf(a[i], b[j], acc[i][j]);
        }
        __syncthreads();
    }
    #pragma unroll
    for (int j = 0; j < 4; ++j) {
        int n = n0 + ng * 4 + j;
        if (n >= N) continue;
        float bv = bias[n];
        #pragma unroll
        for (int i = 0; i < 4; ++i) {
            int m = m0 + mg * 4 + i;
            float v = acc[i][j] + bv;
            if (ACT == 1) v = tanhf(v);
            C[(size_t)m * N + n] = v;
        }
    }
}

// ---------------- prep kernels ----------------
// conv weights [64,48,3] -> wre[64,160] with wre[c][kt*48+e] = w[c][e][kt], zero-padded
__global__ void repack_k(const float* __restrict__ w, float* __restrict__ wre)
{
    int idx = blockIdx.x * 256 + threadIdx.x;             // 64*160
    if (idx >= 64 * KCONV) return;
    int kk = idx % KCONV, c = idx / KCONV;
    float v = 0.0f;
    if (kk < 144) { int kt = kk / 48, e = kk % 48; v = w[(c * 48 + e) * 3 + kt]; }
    wre[idx] = v;
}

// gather char embeddings: ce[(n*16+p)*48 + e] = char_emb[char_ids[n*16+p]][e]
__global__ void ce_k(const int* __restrict__ char_ids, const float* __restrict__ char_emb,
                     float* __restrict__ ce)
{
    size_t idx = (size_t)blockIdx.x * 256 + threadIdx.x;  // 98304*48
    if (idx >= (size_t)NROWS * CLW * CEw) return;
    int e = idx % CEw;
    size_t r = idx / CEw;
    ce[idx] = char_emb[(size_t)char_ids[r] * CEw + e];
}

__global__ void wv_k(const int* __restrict__ wid, const float* __restrict__ wemb,
                     float* __restrict__ enc_in)
{
    size_t idx = (size_t)blockIdx.x * 256 + threadIdx.x;  // NROWS*128
    if (idx >= (size_t)NROWS * 128) return;
    int e = idx & 127; size_t n = idx >> 7;
    enc_in[n * DIN + e] = wemb[(size_t)wid[n] * 128 + e];
}

__global__ void maxrelu_k(const float* __restrict__ y, float* __restrict__ enc_in)
{
    size_t idx = (size_t)blockIdx.x * 256 + threadIdx.x;  // NROWS*64
    if (idx >= (size_t)NROWS * 64) return;
    int c = idx & 63; size_t n = idx >> 6;
    float m = 0.0f;
    #pragma unroll
    for (int p = 0; p < CLW; ++p) m = fmaxf(m, y[(n * CLW + p) * 64 + c]);
    enc_in[n * DIN + 128 + c] = m;                        // relu(max) == max(relu)
}

// whhT4[dir][k][j][gate] f32, gates (i,f,g,o)
__global__ void whht_k(const float* __restrict__ fw, const float* __restrict__ bw,
                       float* __restrict__ out)
{
    int idx = blockIdx.x * 256 + threadIdx.x;             // 2*128*128*4 = 131072
    if (idx >= 131072) return;
    int q = idx & 3, j = (idx >> 2) & 127, k = (idx >> 9) & 127, d = idx >> 16;
    const float* w = d ? bw : fw;
    out[idx] = w[(size_t)(q * 128 + j) * 128 + k];
}

// decoder input-gate table over the 200-char vocab + init prev=BOS
__global__ void gitab_k(const float* __restrict__ lemb, const float* __restrict__ wih,
                        const float* __restrict__ bih, float* __restrict__ git,
                        int* __restrict__ prev)
{
    int idx = blockIdx.x * 256 + threadIdx.x;             // 200*768 = 153600
    if (idx < NROWS) prev[idx] = 3;                       // BOS
    if (idx >= VCD * 768) return;
    int g = idx % 768, v = idx / 768;
    float s = bih[g];
    #pragma unroll
    for (int k = 0; k < CEw; ++k) s = fmaf(lemb[v * CEw + k], wih[(size_t)g * CEw + k], s);
    git[idx] = s;
}

// ---------------- BiLSTM recurrence: 64 blocks = 2 dirs x 32 row-pairs ----------------
__global__ __launch_bounds__(256)
void lstm_k(const float* __restrict__ gi2, const float* __restrict__ whht, float* __restrict__ enc)
{
    int dir = blockIdx.x >> 5, bg = blockIdx.x & 31;
    int tid = threadIdx.x;
    int j = tid & 127, r = tid >> 7;
    int b = bg * 2 + r;
    const float* gi = gi2 + (size_t)dir * NROWS * 512;
    const f4* wt = (const f4*)(whht + (size_t)dir * 128 * 128 * 4);
    __shared__ float h_lds[2][128];
    h_lds[r][j] = 0.0f;
    float c = 0.0f;
    __syncthreads();
    for (int s = 0; s < TSEQ; ++s) {
        int t = dir ? (TSEQ - 1 - s) : s;
        size_t n = (size_t)b * TSEQ + t;
        const float* grow = gi + n * 512;
        float ai = grow[j], af = grow[128 + j], ag = grow[256 + j], ao = grow[384 + j];
        #pragma unroll 4
        for (int k = 0; k < 128; ++k) {
            f4 w = wt[k * 128 + j];
            float hk = h_lds[r][k];
            ai = fmaf(w.x, hk, ai); af = fmaf(w.y, hk, af);
            ag = fmaf(w.z, hk, ag); ao = fmaf(w.w, hk, ao);
        }
        c = sigf(af) * c + sigf(ai) * tanhf(ag);
        float h = sigf(ao) * tanhf(c);
        __syncthreads();
        h_lds[r][j] = h;
        enc[n * HH + dir * 128 + j] = h;
        __syncthreads();
    }
}

// ---------------- GRU pointwise update ----------------
__global__ __launch_bounds__(256)
void upd_k(const float* __restrict__ gh, const float* __restrict__ git,
           const int* __restrict__ prev, float* __restrict__ h)
{
    int n = blockIdx.x, j = threadIdx.x;
    const float* g  = gh + (size_t)n * 768;
    const float* gi = git + (size_t)prev[n] * 768;
    float r  = sigf(gi[j] + g[j]);
    float z  = sigf(gi[256 + j] + g[256 + j]);
    float nn = tanhf(gi[512 + j] + r * g[512 + j]);
    size_t o = (size_t)n * HH + j;
    h[o] = (1.0f - z) * nn + z * h[o];
}

// ---------------- logits write (f32) + argmax (first-index ties) ----------------
__global__ __launch_bounds__(256)
void argmax_k(const float* __restrict__ logits, float* __restrict__ outp,
              int* __restrict__ prev, int step)
{
    int r = threadIdx.x >> 2, q = threadIdx.x & 3;
    int n = blockIdx.x * 64 + r;
    const float* L = logits + (size_t)n * VCD;
    float* O = outp + ((size_t)n * LMAXD + step) * VCD;
    float best = -3.4e38f; int bi = 0;
    int c0 = q * 50;
    for (int i = 0; i < 50; ++i) {
        float v = L[c0 + i];
        O[c0 + i] = v;
        if (v > best) { best = v; bi = c0 + i; }
    }
    __shared__ float sv[64][4];
    __shared__ int   si[64][4];
    sv[r][q] = best; si[r][q] = bi;
    __syncthreads();
    if (q == 0) {
        float b2 = sv[r][0]; int i2 = si[r][0];
        #pragma unroll
        for (int t = 1; t < 4; ++t) if (sv[r][t] > b2) { b2 = sv[r][t]; i2 = si[r][t]; }
        prev[n] = i2;
    }
}

extern "C" void kernel_launch(void* const* d_in, const int* in_sizes, int n_in,
                              void* d_out, int out_size, void* d_ws, size_t ws_size,
                              hipStream_t stream)
{
    const int*   word_ids = (const int*)d_in[0];
    const int*   char_ids = (const int*)d_in[1];
    const float* word_emb = (const float*)d_in[2];
    const float* char_emb = (const float*)d_in[3];
    const float* conv_w   = (const float*)d_in[4];
    const float* conv_b   = (const float*)d_in[5];
    const float* fw_wih   = (const float*)d_in[6];
    const float* fw_whh   = (const float*)d_in[7];
    const float* fw_b     = (const float*)d_in[8];
    const float* bw_wih   = (const float*)d_in[9];
    const float* bw_whh   = (const float*)d_in[10];
    const float* bw_b     = (const float*)d_in[11];
    const float* tag_w    = (const float*)d_in[12];
    const float* tag_b    = (const float*)d_in[13];
    const float* lemma_emb= (const float*)d_in[14];
    const float* init_w   = (const float*)d_in[15];
    const float* init_b   = (const float*)d_in[16];
    const float* gru_wih  = (const float*)d_in[17];
    const float* gru_whh  = (const float*)d_in[18];
    const float* gru_bih  = (const float*)d_in[19];
    const float* gru_bhh  = (const float*)d_in[20];
    const float* proj_w   = (const float*)d_in[21];
    const float* proj_b   = (const float*)d_in[22];

    // ---- workspace layout (lifetime-based aliasing), all f32 ----
    char* ws = (char*)d_ws;
    float* enc_in = (float*)(ws);                      // [6144,192]                     4,718,592 B
    char*  Breg   = ws + 4718592;                      // 25,165,824 B
    float* y      = (float*)Breg;                      // [98304,64]  (conv out)
    float* gi2    = (float*)Breg;                      // [2,6144,512] (overwrites y)
    float* gh     = (float*)Breg;                      // [6144,768]   (decode)
    float* logits = (float*)(Breg + 18874368);         // [6144,200]
    char*  Creg   = ws + 29884416;                     // 18,874,368 B
    float* ce     = (float*)Creg;                      // [98304,48]  (dead after conv)
    float* enc    = (float*)Creg;                      // [6144,256]
    float* hdec   = (float*)(Creg + 6291456);          // [6144,256]
    float* git    = (float*)(Creg + 12582912);         // [200,768]
    float* whht   = (float*)(Creg + 13197312);         // [2,128,128,4]
    int*   prev   = (int*)  (Creg + 13721600);         // [6144]
    float* wre    = (float*)(ws + 48758784);           // [64,160]   (total ws ≈ 48.8 MB)

    float* out_tag = (float*)d_out;                    // [6144,600]
    float* out_lem = out_tag + (size_t)NROWS * NTAGS;  // [6144,24,200]

    // ---- encoder front-end ----
    repack_k<<<40, 256, 0, stream>>>(conv_w, wre);
    ce_k<<<18432, 256, 0, stream>>>(char_ids, char_emb, ce);
    wv_k<<<3072, 256, 0, stream>>>(word_ids, word_emb, enc_in);
    gemm_k<1,0><<<dim3(1536,1), 256, 0, stream>>>(ce, wre, conv_b, y, NROWS*CLW, 64, KCONV);
    maxrelu_k<<<1536, 256, 0, stream>>>(y, enc_in);

    // ---- LSTM input gates (both dirs), then recurrence ----
    gemm_k<0,0><<<dim3(96,8), 256, 0, stream>>>(enc_in, fw_wih, fw_b, gi2, NROWS, 512, DIN);
    gemm_k<0,0><<<dim3(96,8), 256, 0, stream>>>(enc_in, bw_wih, bw_b, gi2 + (size_t)NROWS*512,
                                                NROWS, 512, DIN);
    whht_k<<<512, 256, 0, stream>>>(fw_whh, bw_whh, whht);       // after conv: ce region reused
    gitab_k<<<600, 256, 0, stream>>>(lemma_emb, gru_wih, gru_bih, git, prev);
    lstm_k<<<64, 256, 0, stream>>>(gi2, whht, enc);

    // ---- heads ----
    gemm_k<0,0><<<dim3(96,10), 256, 0, stream>>>(enc, tag_w, tag_b, out_tag, NROWS, NTAGS, HH);
    gemm_k<0,1><<<dim3(96,4), 256, 0, stream>>>(enc, init_w, init_b, hdec, NROWS, HH, HH);

    // ---- greedy GRU decode, 24 steps ----
    for (int s = 0; s < LMAXD; ++s) {
        gemm_k<0,0><<<dim3(96,12), 256, 0, stream>>>(hdec, gru_whh, gru_bhh, gh, NROWS, 768, HH);
        upd_k<<<NROWS, 256, 0, stream>>>(gh, git, prev, hdec);
        gemm_k<0,0><<<dim3(96,4), 256, 0, stream>>>(hdec, proj_w, proj_b, logits, NROWS, VCD, HH);
        argmax_k<<<96, 256, 0, stream>>>(logits, out_lem, prev, s);
    }
}

// Round 4
// 1543.291 us; speedup vs baseline: 1.8416x; 1.8416x over previous
//
#include <hip/hip_runtime.h>
#include <hip/hip_bf16.h>
#include <math.h>

typedef float f4 __attribute__((ext_vector_type(4)));
typedef __attribute__((ext_vector_type(8))) short short8;

#define NTAGS 600
#define CEw   48
#define HH    256
#define BBATCH 64
#define TSEQ  96
#define CLW   16
#define LMAXD 24
#define NROWS (BBATCH*TSEQ)   /* 6144 */
#define DIN   192             /* WE(128)+CC(64) */
#define KCONV 160             /* 144 padded to /32 */
#define VCD   200

__device__ __forceinline__ float sigf(float x){ return 1.0f/(1.0f+expf(-x)); }

// ---------------- generic tiled f32 GEMM: C[M,N] = A[M,K] * B[N,K]^T + bias ----------------
// MODE 0: A row-major [M,K].  MODE 1: conv sliding window over ce rows of 48, K=144 (padded 160).
// ACT: 0 none, 1 tanh.
template<int MODE, int ACT>
__global__ __launch_bounds__(256)
void gemm_k(const float* __restrict__ A, const float* __restrict__ B,
            const float* __restrict__ bias, float* __restrict__ C,
            int M, int N, int K)
{
    __shared__ float As[32][68];
    __shared__ float Bs[32][68];
    const int tid = threadIdx.x;
    const int m0 = blockIdx.x * 64;
    const int n0 = blockIdx.y * 64;
    const int mg = tid >> 4, ng = tid & 15;
    float acc[4][4] = {};
    for (int k0 = 0; k0 < K; k0 += 32) {
        #pragma unroll
        for (int i = 0; i < 8; ++i) {
            int e  = tid + i * 256;
            int kk = e & 31, mm = e >> 5;
            int m = m0 + mm;
            int k = k0 + kk;
            float av;
            if (MODE == 0) {
                av = A[(size_t)m * K + k];
            } else {
                av = 0.0f;
                int p = m & 15;
                if (k < 144 && !(p == 0 && k < 48) && !(p == 15 && k >= 96))
                    av = A[m * 48 + k - 48];
            }
            As[kk][mm] = av;
            int n = n0 + mm;
            Bs[kk][mm] = (n < N) ? B[(size_t)n * K + k] : 0.0f;
        }
        __syncthreads();
        #pragma unroll
        for (int kk = 0; kk < 32; ++kk) {
            f4 a = *reinterpret_cast<const f4*>(&As[kk][mg * 4]);
            f4 b = *reinterpret_cast<const f4*>(&Bs[kk][ng * 4]);
            #pragma unroll
            for (int i = 0; i < 4; ++i)
                #pragma unroll
                for (int j = 0; j < 4; ++j)
                    acc[i][j] = fmaf(a[i], b[j], acc[i][j]);
        }
        __syncthreads();
    }
    #pragma unroll
    for (int j = 0; j < 4; ++j) {
        int n = n0 + ng * 4 + j;
        if (n >= N) continue;
        float bv = bias[n];
        #pragma unroll
        for (int i = 0; i < 4; ++i) {
            int m = m0 + mg * 4 + i;
            float v = acc[i][j] + bv;
            if (ACT == 1) v = tanhf(v);
            C[(size_t)m * N + n] = v;
        }
    }
}

// ---------------- MFMA 3-term split GEMM: C = A@B^T + bias, f32-accurate via bf16 planes ----
// A planes: Ahi/Alo row-major [M,256] bf16. B planes: Bhi/Blo row-major [Npad,256] bf16.
// Virtual K=768: seg0 Ahi*Bhi, seg1 Alo*Bhi, seg2 Ahi*Blo  (drops only Alo*Blo ~ 2^-18).
__global__ __launch_bounds__(256)
void gemm_mx_k(const ushort* __restrict__ Ahi, const ushort* __restrict__ Alo,
               const ushort* __restrict__ Bhi, const ushort* __restrict__ Blo,
               const float* __restrict__ bias, float* __restrict__ C, int Nc, int ldC)
{
    __shared__ ushort As[128 * 64];
    __shared__ ushort Bs[128 * 64];
    const int tid = threadIdx.x;
    const int m0 = blockIdx.x * 128;
    const int n0 = blockIdx.y * 128;
    const int w = tid >> 6, l = tid & 63;
    const int wr = (w >> 1) * 64, wc = (w & 1) * 64;
    f4 acc[4][4];
    #pragma unroll
    for (int i = 0; i < 4; ++i)
        #pragma unroll
        for (int j = 0; j < 4; ++j)
            acc[i][j] = (f4){0.f, 0.f, 0.f, 0.f};

    #pragma unroll
    for (int seg = 0; seg < 3; ++seg) {
        const ushort* Ap = (seg == 1) ? Alo : Ahi;
        const ushort* Bp = (seg == 2) ? Blo : Bhi;
        #pragma unroll
        for (int ka = 0; ka < 256; ka += 64) {
            #pragma unroll
            for (int i = 0; i < 4; ++i) {
                int c = w * 4 + i;                 // chunk 0..15, 1KB each
                int row = c * 8 + (l >> 3);
                int col16 = l & 7;
                __builtin_amdgcn_global_load_lds(
                    (const __attribute__((address_space(1))) void*)(Ap + (size_t)(m0 + row) * 256 + ka + col16 * 8),
                    (__attribute__((address_space(3))) void*)((char*)As + c * 1024 + l * 16),
                    16, 0, 0);
                __builtin_amdgcn_global_load_lds(
                    (const __attribute__((address_space(1))) void*)(Bp + (size_t)(n0 + row) * 256 + ka + col16 * 8),
                    (__attribute__((address_space(3))) void*)((char*)Bs + c * 1024 + l * 16),
                    16, 0, 0);
            }
            __syncthreads();
            #pragma unroll
            for (int kk = 0; kk < 64; kk += 32) {
                short8 a[4], b[4];
                #pragma unroll
                for (int mf = 0; mf < 4; ++mf)
                    a[mf] = *(const short8*)(As + (wr + mf * 16 + (l & 15)) * 64 + kk + (l >> 4) * 8);
                #pragma unroll
                for (int nf = 0; nf < 4; ++nf)
                    b[nf] = *(const short8*)(Bs + (wc + nf * 16 + (l & 15)) * 64 + kk + (l >> 4) * 8);
                #pragma unroll
                for (int mf = 0; mf < 4; ++mf)
                    #pragma unroll
                    for (int nf = 0; nf < 4; ++nf)
                        acc[mf][nf] = __builtin_amdgcn_mfma_f32_16x16x32_bf16(a[mf], b[nf], acc[mf][nf], 0, 0, 0);
            }
            __syncthreads();
        }
    }
    #pragma unroll
    for (int nf = 0; nf < 4; ++nf) {
        int n = n0 + wc + nf * 16 + (l & 15);
        if (n >= Nc) continue;
        float bv = bias[n];
        #pragma unroll
        for (int mf = 0; mf < 4; ++mf) {
            int mrow = m0 + wr + mf * 16 + (l >> 4) * 4;
            #pragma unroll
            for (int q2 = 0; q2 < 4; ++q2)
                C[(size_t)(mrow + q2) * ldC + n] = acc[mf][nf][q2] + bv;
        }
    }
}

// ---------------- prep kernels ----------------
__global__ void repack_k(const float* __restrict__ w, float* __restrict__ wre)
{
    int idx = blockIdx.x * 256 + threadIdx.x;             // 64*160
    if (idx >= 64 * KCONV) return;
    int kk = idx % KCONV, c = idx / KCONV;
    float v = 0.0f;
    if (kk < 144) { int kt = kk / 48, e = kk % 48; v = w[(c * 48 + e) * 3 + kt]; }
    wre[idx] = v;
}

__global__ void ce_k(const int* __restrict__ char_ids, const float* __restrict__ char_emb,
                     float* __restrict__ ce)
{
    size_t idx = (size_t)blockIdx.x * 256 + threadIdx.x;  // 98304*48
    if (idx >= (size_t)NROWS * CLW * CEw) return;
    int e = idx % CEw;
    size_t r = idx / CEw;
    ce[idx] = char_emb[(size_t)char_ids[r] * CEw + e];
}

__global__ void wv_k(const int* __restrict__ wid, const float* __restrict__ wemb,
                     float* __restrict__ enc_in)
{
    size_t idx = (size_t)blockIdx.x * 256 + threadIdx.x;  // NROWS*128
    if (idx >= (size_t)NROWS * 128) return;
    int e = idx & 127; size_t n = idx >> 7;
    enc_in[n * DIN + e] = wemb[(size_t)wid[n] * 128 + e];
}

__global__ void maxrelu_k(const float* __restrict__ y, float* __restrict__ enc_in)
{
    size_t idx = (size_t)blockIdx.x * 256 + threadIdx.x;  // NROWS*64
    if (idx >= (size_t)NROWS * 64) return;
    int c = idx & 63; size_t n = idx >> 6;
    float m = 0.0f;
    #pragma unroll
    for (int p = 0; p < CLW; ++p) m = fmaxf(m, y[(n * CLW + p) * 64 + c]);
    enc_in[n * DIN + 128 + c] = m;
}

// whhT4[dir][k][j][gate] f32, gates (i,f,g,o)
__global__ void whht_k(const float* __restrict__ fw, const float* __restrict__ bw,
                       float* __restrict__ out)
{
    int idx = blockIdx.x * 256 + threadIdx.x;             // 2*128*128*4 = 131072
    if (idx >= 131072) return;
    int q = idx & 3, j = (idx >> 2) & 127, k = (idx >> 9) & 127, d = idx >> 16;
    const float* w = d ? bw : fw;
    out[idx] = w[(size_t)(q * 128 + j) * 128 + k];
}

__global__ void gitab_k(const float* __restrict__ lemb, const float* __restrict__ wih,
                        const float* __restrict__ bih, float* __restrict__ git,
                        int* __restrict__ prev)
{
    int idx = blockIdx.x * 256 + threadIdx.x;             // 200*768
    if (idx < NROWS) prev[idx] = 3;                       // BOS
    if (idx >= VCD * 768) return;
    int g = idx % 768, v = idx / 768;
    float s = bih[g];
    #pragma unroll
    for (int k = 0; k < CEw; ++k) s = fmaf(lemb[v * CEw + k], wih[(size_t)g * CEw + k], s);
    git[idx] = s;
}

// split f32 weight [rows,256] -> bf16 planes [2][rowsPad][256] (hi plane, then lo plane)
__global__ void wsplit_k(const float* __restrict__ W, __hip_bfloat16* __restrict__ out,
                         int rows, int rowsPad)
{
    int idx = blockIdx.x * 256 + threadIdx.x;
    if (idx >= rowsPad * 256) return;
    int r = idx >> 8, k = idx & 255;
    float v = (r < rows) ? W[(size_t)r * 256 + k] : 0.0f;
    __hip_bfloat16 hi = __float2bfloat16(v);
    out[idx] = hi;
    out[rowsPad * 256 + idx] = __float2bfloat16(v - __bfloat162float(hi));
}

__global__ void hsplit_k(const float* __restrict__ h, __hip_bfloat16* __restrict__ hhi,
                         __hip_bfloat16* __restrict__ hlo)
{
    int idx = blockIdx.x * 256 + threadIdx.x;             // 6144*256
    float v = h[idx];
    __hip_bfloat16 hi = __float2bfloat16(v);
    hhi[idx] = hi;
    hlo[idx] = __float2bfloat16(v - __bfloat162float(hi));
}

// ---------------- BiLSTM recurrence: 128 blocks = dir x batch, 1024 thr, split-k=8 ----------
__global__ __launch_bounds__(1024, 4)
void lstm_k(const float* __restrict__ gi2, const float* __restrict__ whht, float* __restrict__ enc)
{
    const int dir = blockIdx.x >> 6, b = blockIdx.x & 63;
    const int tid = threadIdx.x;
    const int j = tid & 127, q = tid >> 7;                // q = k-group 0..7
    const float* gi = gi2 + (size_t)dir * NROWS * 512;
    const f4* wt = (const f4*)(whht + (size_t)dir * 65536);
    f4 wreg[16];
    #pragma unroll
    for (int kk = 0; kk < 16; ++kk) wreg[kk] = wt[(q * 16 + kk) * 128 + j];
    __shared__ float hbuf[128];
    __shared__ f4 part[8][128];
    float c = 0.0f;
    if (tid < 128) hbuf[tid] = 0.0f;
    __syncthreads();
    for (int s = 0; s < TSEQ; ++s) {
        int t = dir ? (TSEQ - 1 - s) : s;
        size_t n = (size_t)b * TSEQ + t;
        const float* grow = gi + n * 512;
        float ai = 0.f, af = 0.f, ag = 0.f, ao = 0.f;
        if (q == 0) { ai = grow[j]; af = grow[128 + j]; ag = grow[256 + j]; ao = grow[384 + j]; }
        const f4* hb = (const f4*)(hbuf + q * 16);
        f4 h0 = hb[0], h1 = hb[1], h2 = hb[2], h3 = hb[3];
        f4 hh[4] = {h0, h1, h2, h3};
        f4 p = (f4){0.f, 0.f, 0.f, 0.f};
        #pragma unroll
        for (int kk = 0; kk < 16; ++kk) {
            float hv = hh[kk >> 2][kk & 3];
            p.x = fmaf(wreg[kk].x, hv, p.x);
            p.y = fmaf(wreg[kk].y, hv, p.y);
            p.z = fmaf(wreg[kk].z, hv, p.z);
            p.w = fmaf(wreg[kk].w, hv, p.w);
        }
        part[q][j] = p;
        __syncthreads();
        if (q == 0) {
            f4 sum = part[0][j];
            #pragma unroll
            for (int qq = 1; qq < 8; ++qq) {
                f4 pp = part[qq][j];
                sum.x += pp.x; sum.y += pp.y; sum.z += pp.z; sum.w += pp.w;
            }
            ai += sum.x; af += sum.y; ag += sum.z; ao += sum.w;
            c = sigf(af) * c + sigf(ai) * tanhf(ag);
            float h = sigf(ao) * tanhf(c);
            hbuf[j] = h;
            enc[n * HH + dir * 128 + j] = h;
        }
        __syncthreads();
    }
}

// ---------------- GRU pointwise update (+ bf16 hi/lo split of new h) ----------------
__global__ __launch_bounds__(256)
void upd_k(const float* __restrict__ gh, const float* __restrict__ git,
           const int* __restrict__ prev, float* __restrict__ h,
           __hip_bfloat16* __restrict__ hhi, __hip_bfloat16* __restrict__ hlo)
{
    int n = blockIdx.x, j = threadIdx.x;
    const float* g  = gh + (size_t)n * 768;
    const float* gi = git + (size_t)prev[n] * 768;
    float r  = sigf(gi[j] + g[j]);
    float z  = sigf(gi[256 + j] + g[256 + j]);
    float nn = tanhf(gi[512 + j] + r * g[512 + j]);
    size_t o = (size_t)n * HH + j;
    float hv = (1.0f - z) * nn + z * h[o];
    h[o] = hv;
    __hip_bfloat16 hi = __float2bfloat16(hv);
    hhi[o] = hi;
    hlo[o] = __float2bfloat16(hv - __bfloat162float(hi));
}

// ---------------- logits write (f32) + argmax (first-index ties) ----------------
__global__ __launch_bounds__(256)
void argmax_k(const float* __restrict__ logits, float* __restrict__ outp,
              int* __restrict__ prev, int step)
{
    int r = threadIdx.x >> 2, q = threadIdx.x & 3;
    int n = blockIdx.x * 64 + r;
    const float* L = logits + (size_t)n * VCD;
    float* O = outp + ((size_t)n * LMAXD + step) * VCD;
    float best = -3.4e38f; int bi = 0;
    int c0 = q * 50;
    for (int i = 0; i < 50; ++i) {
        float v = L[c0 + i];
        O[c0 + i] = v;
        if (v > best) { best = v; bi = c0 + i; }
    }
    __shared__ float sv[64][4];
    __shared__ int   si[64][4];
    sv[r][q] = best; si[r][q] = bi;
    __syncthreads();
    if (q == 0) {
        float b2 = sv[r][0]; int i2 = si[r][0];
        #pragma unroll
        for (int t = 1; t < 4; ++t) if (sv[r][t] > b2) { b2 = sv[r][t]; i2 = si[r][t]; }
        prev[n] = i2;
    }
}

extern "C" void kernel_launch(void* const* d_in, const int* in_sizes, int n_in,
                              void* d_out, int out_size, void* d_ws, size_t ws_size,
                              hipStream_t stream)
{
    const int*   word_ids = (const int*)d_in[0];
    const int*   char_ids = (const int*)d_in[1];
    const float* word_emb = (const float*)d_in[2];
    const float* char_emb = (const float*)d_in[3];
    const float* conv_w   = (const float*)d_in[4];
    const float* conv_b   = (const float*)d_in[5];
    const float* fw_wih   = (const float*)d_in[6];
    const float* fw_whh   = (const float*)d_in[7];
    const float* fw_b     = (const float*)d_in[8];
    const float* bw_wih   = (const float*)d_in[9];
    const float* bw_whh   = (const float*)d_in[10];
    const float* bw_b     = (const float*)d_in[11];
    const float* tag_w    = (const float*)d_in[12];
    const float* tag_b    = (const float*)d_in[13];
    const float* lemma_emb= (const float*)d_in[14];
    const float* init_w   = (const float*)d_in[15];
    const float* init_b   = (const float*)d_in[16];
    const float* gru_wih  = (const float*)d_in[17];
    const float* gru_whh  = (const float*)d_in[18];
    const float* gru_bih  = (const float*)d_in[19];
    const float* gru_bhh  = (const float*)d_in[20];
    const float* proj_w   = (const float*)d_in[21];
    const float* proj_b   = (const float*)d_in[22];

    // ---- workspace layout (lifetime-based aliasing) ----
    char* ws = (char*)d_ws;
    float* enc_in = (float*)(ws);                      // [6144,192] f32 (front-end)
    __hip_bfloat16* h_hi = (__hip_bfloat16*)ws;        // [6144,256] bf16 (decode; reuses enc_in)
    char*  Breg   = ws + 4718592;                      // 25,165,824 B
    float* y      = (float*)Breg;                      // conv out [98304,64]
    float* gi2    = (float*)Breg;                      // [2,6144,512]
    float* gh     = (float*)Breg;                      // [6144,768] (decode)
    float* logits = (float*)(Breg + 18874368);         // [6144,200]
    char*  Creg   = ws + 29884416;                     // 18,874,368 B
    float* ce     = (float*)Creg;                      // [98304,48] (dead after conv)
    float* enc    = (float*)Creg;                      // [6144,256]
    float* hdec   = (float*)(Creg + 6291456);          // [6144,256]
    float* git    = (float*)(Creg + 12582912);         // [200,768]
    float* whht   = (float*)(Creg + 13197312);         // [2,128,128,4]
    int*   prev   = (int*)  (Creg + 13721600);         // [6144]
    __hip_bfloat16* h_lo     = (__hip_bfloat16*)(Creg + 13746176);  // [6144,256]
    __hip_bfloat16* whh_ext  = (__hip_bfloat16*)(Creg + 16891904);  // [2][768][256]
    __hip_bfloat16* proj_ext = (__hip_bfloat16*)(Creg + 17678336);  // [2][256][256]
    float* wre    = (float*)(ws + 48758784);           // [64,160]

    float* out_tag = (float*)d_out;                    // [6144,600]
    float* out_lem = out_tag + (size_t)NROWS * NTAGS;  // [6144,24,200]

    // ---- encoder front-end ----
    repack_k<<<40, 256, 0, stream>>>(conv_w, wre);
    ce_k<<<18432, 256, 0, stream>>>(char_ids, char_emb, ce);
    wv_k<<<3072, 256, 0, stream>>>(word_ids, word_emb, enc_in);
    gemm_k<1,0><<<dim3(1536,1), 256, 0, stream>>>(ce, wre, conv_b, y, NROWS*CLW, 64, KCONV);
    maxrelu_k<<<1536, 256, 0, stream>>>(y, enc_in);

    // ---- LSTM input gates (both dirs), then recurrence ----
    gemm_k<0,0><<<dim3(96,8), 256, 0, stream>>>(enc_in, fw_wih, fw_b, gi2, NROWS, 512, DIN);
    gemm_k<0,0><<<dim3(96,8), 256, 0, stream>>>(enc_in, bw_wih, bw_b, gi2 + (size_t)NROWS*512,
                                                NROWS, 512, DIN);
    whht_k<<<512, 256, 0, stream>>>(fw_whh, bw_whh, whht);
    gitab_k<<<600, 256, 0, stream>>>(lemma_emb, gru_wih, gru_bih, git, prev);
    wsplit_k<<<768, 256, 0, stream>>>(gru_whh, whh_ext, 768, 768);
    wsplit_k<<<256, 256, 0, stream>>>(proj_w, proj_ext, 200, 256);
    lstm_k<<<128, 1024, 0, stream>>>(gi2, whht, enc);

    // ---- heads ----
    gemm_k<0,0><<<dim3(96,10), 256, 0, stream>>>(enc, tag_w, tag_b, out_tag, NROWS, NTAGS, HH);
    gemm_k<0,1><<<dim3(96,4), 256, 0, stream>>>(enc, init_w, init_b, hdec, NROWS, HH, HH);
    hsplit_k<<<6144, 256, 0, stream>>>(hdec, h_hi, h_lo);

    // ---- greedy GRU decode, 24 steps (MFMA 3-term split GEMMs) ----
    const ushort* whh_hi  = (const ushort*)whh_ext;
    const ushort* whh_lo  = whh_hi + 768 * 256;
    const ushort* proj_hi = (const ushort*)proj_ext;
    const ushort* proj_lo = proj_hi + 256 * 256;
    for (int s = 0; s < LMAXD; ++s) {
        gemm_mx_k<<<dim3(48,6), 256, 0, stream>>>((const ushort*)h_hi, (const ushort*)h_lo,
                                                  whh_hi, whh_lo, gru_bhh, gh, 768, 768);
        upd_k<<<NROWS, 256, 0, stream>>>(gh, git, prev, hdec, h_hi, h_lo);
        gemm_mx_k<<<dim3(48,2), 256, 0, stream>>>((const ushort*)h_hi, (const ushort*)h_lo,
                                                  proj_hi, proj_lo, proj_b, logits, 200, 200);
        argmax_k<<<96, 256, 0, stream>>>(logits, out_lem, prev, s);
    }
}